// Round 2
// baseline (14075.334 us; speedup 1.0000x reference)
//
#include <hip/hip_runtime.h>
#include <hip/hip_fp16.h>

namespace {

constexpr int kIn  = 64;
constexpr int kHid = 128;
constexpr int kOut = 64;
constexpr int kT   = 1000;
constexpr int kTC  = 8;
constexpr int kBatch = 256;

__device__ __forceinline__ float sigm(float v)  { return 1.0f / (1.0f + __expf(-v)); }
__device__ __forceinline__ float tanh_(float v) { return 2.0f / (1.0f + __expf(-2.0f * v)) - 1.0f; }

// Full-K dot of f32 vector (LDS, wave-broadcast reads) against register-resident
// f16 weight pairs. fmaf(float(half), f32, f32) folds to v_fma_mix_f32.
// 4 accumulators break the dependent-FMA chain (4-cyc latency each).
template<int N4, int WOFF>
__device__ __forceinline__ float dotK(const float* __restrict__ v, const __half2* w) {
  const float4* v4 = reinterpret_cast<const float4*>(v);
  float a0 = 0.f, a1 = 0.f, a2 = 0.f, a3 = 0.f;
#pragma unroll
  for (int g = 0; g < N4; ++g) {
    const float4 uv = v4[g];
    const __half2 w0 = w[WOFF + 2 * g];
    const __half2 w1 = w[WOFF + 2 * g + 1];
    a0 = fmaf(__low2float(w0),  uv.x, a0);
    a1 = fmaf(__high2float(w0), uv.y, a1);
    a2 = fmaf(__low2float(w1),  uv.z, a2);
    a3 = fmaf(__high2float(w1), uv.w, a3);
  }
  return (a0 + a2) + (a1 + a3);
}

// One block per batch row; 512 threads = 8 waves. One thread owns entire
// output columns (weights in VGPRs as f16 pairs) -> no partial-sum reduction,
// only 2 barriers per timestep.
__global__ __launch_bounds__(512, 2) void grud_persistent(
    const float* __restrict__ gIn,
    const float* __restrict__ xMean,
    const float* __restrict__ Wdgx, const float* __restrict__ bdgx,
    const float* __restrict__ Wdgh, const float* __restrict__ bdgh,
    const float* __restrict__ Wxz,  const float* __restrict__ Whz,
    const float* __restrict__ Wmz,  const float* __restrict__ bmz,
    const float* __restrict__ Wxr,  const float* __restrict__ Whr,
    const float* __restrict__ Wmr,
    const float* __restrict__ Wxh,  const float* __restrict__ Whh,
    const float* __restrict__ Wmh,  const float* __restrict__ bmh,
    const float* __restrict__ Why,  const float* __restrict__ bhy,
    float* __restrict__ out)
{
  const int tid = threadIdx.x;
  const int b   = blockIdx.x;

  // ---------------- LDS ----------------
  __shared__ __align__(16) float sX[2][kTC][kIn];   // double-buffered staging
  __shared__ __align__(16) float sM[2][kTC][kIn];
  __shared__ __align__(16) float sD[2][kTC][kIn];
  __shared__ __align__(16) float su[256];           // [x'(64) | m(64) | h'=gamma_h*h (128)]
  __shared__ __align__(16) float sh[kHid];          // h(t) (read only by y threads)
  __shared__ __align__(16) float srh[kHid];         // r * h'
  __shared__ __align__(16) float sz[kHid];          // z gate

  // ---- register-resident weight columns (f16 pairs) ----
  // tid 0-127  : z col j=tid        -> [Wxz|Wmz|Whz] at wcol[0..127]
  // tid 128-255: r col j=tid-128    -> [Wxr|Wmr|Whr] at wcol[0..127]
  // tid 256-383: j=tid-256          -> [Wxh|Wmh] at [0..63], Whh at [64..127], Wdgh at [128..159]
  // tid 384-447: i=tid-384          -> Wdgx at [0..31]
  // tid 448-511: o=tid-448          -> Why  at [0..63]
  __half2 wcol[160];

  if (tid < 256) {
    const int j = tid & 127;
    const float* Wx = (tid < 128) ? Wxz : Wxr;
    const float* Wm = (tid < 128) ? Wmz : Wmr;
    const float* Wh = (tid < 128) ? Whz : Whr;
#pragma unroll
    for (int k = 0; k < 32; ++k)
      wcol[k] = __floats2half2_rn(Wx[(2 * k) * kHid + j], Wx[(2 * k + 1) * kHid + j]);
#pragma unroll
    for (int k = 0; k < 32; ++k)
      wcol[32 + k] = __floats2half2_rn(Wm[(2 * k) * kHid + j], Wm[(2 * k + 1) * kHid + j]);
#pragma unroll
    for (int k = 0; k < 64; ++k)
      wcol[64 + k] = __floats2half2_rn(Wh[(2 * k) * kHid + j], Wh[(2 * k + 1) * kHid + j]);
  } else if (tid < 384) {
    const int j = tid - 256;
#pragma unroll
    for (int k = 0; k < 32; ++k)
      wcol[k] = __floats2half2_rn(Wxh[(2 * k) * kHid + j], Wxh[(2 * k + 1) * kHid + j]);
#pragma unroll
    for (int k = 0; k < 32; ++k)
      wcol[32 + k] = __floats2half2_rn(Wmh[(2 * k) * kHid + j], Wmh[(2 * k + 1) * kHid + j]);
#pragma unroll
    for (int k = 0; k < 64; ++k)
      wcol[64 + k] = __floats2half2_rn(Whh[(2 * k) * kHid + j], Whh[(2 * k + 1) * kHid + j]);
#pragma unroll
    for (int k = 0; k < 32; ++k)
      wcol[128 + k] = __floats2half2_rn(Wdgh[(2 * k) * kHid + j], Wdgh[(2 * k + 1) * kHid + j]);
  } else if (tid < 448) {
    const int i = tid - 384;
#pragma unroll
    for (int k = 0; k < 32; ++k)
      wcol[k] = __floats2half2_rn(Wdgx[(2 * k) * kIn + i], Wdgx[(2 * k + 1) * kIn + i]);
  } else {
    const int o = tid - 448;
#pragma unroll
    for (int k = 0; k < 64; ++k)
      wcol[k] = __floats2half2_rn(Why[(2 * k) * kOut + o], Why[(2 * k + 1) * kOut + o]);
  }

  // per-thread scalar state
  float bz = 0.f, bha = 0.f, bgh = 0.f, bgx = 0.f, xm = 0.f, by = 0.f;
  float xlReg = 0.f, haReg = 0.f;
  if (tid < 128)       { bz = bmz[tid]; }
  else if (tid >= 256 && tid < 384) { bha = bmh[tid - 256]; bgh = bdgh[tid - 256]; }
  else if (tid >= 384 && tid < 448) { bgx = bdgx[tid - 384]; xm = xMean[tid - 384]; }
  else if (tid >= 448) { by = bhy[tid - 448]; }

  const float* gBase = gIn + (size_t)b * 3 * kIn * kT;
  float* outY = out + (size_t)b * kT * kOut;
  float* outH = out + (size_t)kBatch * kT * kOut + (size_t)b * kT * kHid;

  // ---------------- prologue ----------------
  // stage chunk 0 into buffer 0 (threads 0-191, coalesced float4 along t)
  if (tid < 192) {
    const int arr = tid >> 6, i = tid & 63;
    const float4* s4 = reinterpret_cast<const float4*>(gBase + (size_t)(arr * kIn + i) * kT);
    const float4 v0 = s4[0], v1 = s4[1];
    float* dst = (arr == 0) ? &sX[0][0][0] : (arr == 1) ? &sM[0][0][0] : &sD[0][0][0];
    dst[0 * kIn + i] = v0.x; dst[1 * kIn + i] = v0.y; dst[2 * kIn + i] = v0.z; dst[3 * kIn + i] = v0.w;
    dst[4 * kIn + i] = v1.x; dst[5 * kIn + i] = v1.y; dst[6 * kIn + i] = v1.z; dst[7 * kIn + i] = v1.w;
  }
  if (tid >= 256 && tid < 384) su[128 + (tid - 256)] = 0.f;  // h'(0) = gamma_h*h(-1) = 0
  __syncthreads();
  // x'(0) (needs staged chunk 0)
  if (tid >= 384 && tid < 448) {
    const int i = tid - 384;
    const float gd = dotK<16, 0>(&sD[0][0][0], wcol) + bgx;
    const float gx = __expf(-fmaxf(gd, 0.f));
    const float x = sX[0][0][i], m = sM[0][0][i];
    const float xlv = (m > 0.f) ? x : xlReg;
    xlReg = xlv;
    su[i]      = m * x + (1.f - m) * (gx * xlv + (1.f - gx) * xm);
    su[64 + i] = m;
  }
  __syncthreads();

  // ---------------- main loop: 2 barriers per step ----------------
#pragma unroll 1
  for (int t = 0; t < kT; ++t) {
    // ---- window P2: z / r / ha dots; y(t-1); staging ----
    if (tid < 128) {
      sz[tid] = sigm(dotK<64, 0>(su, wcol) + bz);
    } else if (tid < 256) {
      const int j = tid - 128;
      const float rr = sigm(dotK<64, 0>(su, wcol));   // r has no bias
      srh[j] = rr * su[128 + j];
    } else if (tid < 384) {
      haReg = dotK<32, 0>(su, wcol) + bha;            // [x';m] part of h_tilde
    } else {
      if ((t & 7) == 0) {
        const int c = t >> 3;
        if (c < 124) {                                // stage chunk c+1
          const int nb = (c + 1) & 1, tn0 = t + 8, lt = tid - 384;
          {
            const int p = lt, arr = p >> 6, i = p & 63;
            const float4* s4 = reinterpret_cast<const float4*>(gBase + (size_t)(arr * kIn + i) * kT + tn0);
            const float4 v0 = s4[0], v1 = s4[1];
            float* dst = (arr == 0) ? &sX[nb][0][0] : (arr == 1) ? &sM[nb][0][0] : &sD[nb][0][0];
            dst[0 * kIn + i] = v0.x; dst[1 * kIn + i] = v0.y; dst[2 * kIn + i] = v0.z; dst[3 * kIn + i] = v0.w;
            dst[4 * kIn + i] = v1.x; dst[5 * kIn + i] = v1.y; dst[6 * kIn + i] = v1.z; dst[7 * kIn + i] = v1.w;
          }
          if (lt < 64) {                              // remaining third (arr==2)
            const int i = lt;
            const float4* s4 = reinterpret_cast<const float4*>(gBase + (size_t)(2 * kIn + i) * kT + tn0);
            const float4 v0 = s4[0], v1 = s4[1];
            float* dst = &sD[nb][0][0];
            dst[0 * kIn + i] = v0.x; dst[1 * kIn + i] = v0.y; dst[2 * kIn + i] = v0.z; dst[3 * kIn + i] = v0.w;
            dst[4 * kIn + i] = v1.x; dst[5 * kIn + i] = v1.y; dst[6 * kIn + i] = v1.z; dst[7 * kIn + i] = v1.w;
          }
        }
      }
      if (tid >= 448 && t > 0) {                      // y(t-1) from h(t-1) in sh
        const int o = tid - 448;
        outY[(size_t)(t - 1) * kOut + o] = sigm(dotK<32, 0>(sh, wcol) + by);
      }
    }
    __syncthreads();

    // ---- window P3: hh dot + h update + gamma(t+1) + x'(t+1) ----
    {
      const int tn = t + 1, nb = (tn >> 3) & 1, ttn = tn & 7;
      if (tid >= 256 && tid < 384) {
        const int j = tid - 256;
        const float s  = haReg + dotK<32, 64>(srh, wcol);
        const float ht = tanh_(s);
        const float zz = sz[j];
        const float hp = su[128 + j];
        const float hn = (1.f - zz) * hp + zz * ht;
        outH[(size_t)t * kHid + j] = hn;
        sh[j] = hn;
        float ghn = 0.f;
        if (tn < kT) {
          const float gd = dotK<16, 128>(&sD[nb][ttn][0], wcol) + bgh;
          ghn = __expf(-fmaxf(gd, 0.f));
        }
        su[128 + j] = ghn * hn;                       // h'(t+1), read at P2(t+1)
      } else if (tid >= 384 && tid < 448 && tn < kT) {
        const int i = tid - 384;
        const float gd = dotK<16, 0>(&sD[nb][ttn][0], wcol) + bgx;
        const float gx = __expf(-fmaxf(gd, 0.f));
        const float x = sX[nb][ttn][i], m = sM[nb][ttn][i];
        const float xlv = (m > 0.f) ? x : xlReg;
        xlReg = xlv;
        su[i]      = m * x + (1.f - m) * (gx * xlv + (1.f - gx) * xm);
        su[64 + i] = m;
      }
    }
    __syncthreads();
  }

  // ---------------- epilogue: y(999) ----------------
  if (tid >= 448) {
    const int o = tid - 448;
    outY[(size_t)(kT - 1) * kOut + o] = sigm(dotK<32, 0>(sh, wcol) + by);
  }
}

} // namespace

extern "C" void kernel_launch(void* const* d_in, const int* in_sizes, int n_in,
                              void* d_out, int out_size, void* d_ws, size_t ws_size,
                              hipStream_t stream) {
  const float* gIn   = (const float*)d_in[0];
  const float* xMean = (const float*)d_in[1];
  const float* Wdgx  = (const float*)d_in[2];
  const float* bdgx  = (const float*)d_in[3];
  const float* Wdgh  = (const float*)d_in[4];
  const float* bdgh  = (const float*)d_in[5];
  const float* Wxz   = (const float*)d_in[6];
  const float* Whz   = (const float*)d_in[7];
  const float* Wmz   = (const float*)d_in[8];
  const float* bmz   = (const float*)d_in[9];
  const float* Wxr   = (const float*)d_in[10];
  const float* Whr   = (const float*)d_in[11];
  const float* Wmr   = (const float*)d_in[12];
  const float* Wxh   = (const float*)d_in[13];
  const float* Whh   = (const float*)d_in[14];
  const float* Wmh   = (const float*)d_in[15];
  const float* bmh   = (const float*)d_in[16];
  const float* Why   = (const float*)d_in[17];
  const float* bhy   = (const float*)d_in[18];

  grud_persistent<<<dim3(kBatch), dim3(512), 0, stream>>>(
      gIn, xMean, Wdgx, bdgx, Wdgh, bdgh, Wxz, Whz, Wmz, bmz,
      Wxr, Whr, Wmr, Wxh, Whh, Wmh, bmh, Why, bhy, (float*)d_out);
}